// Round 1
// baseline (2081.671 us; speedup 1.0000x reference)
//
#include <hip/hip_runtime.h>
#include <limits.h>
#include <cstdint>

#define TE 64

// ---------------------------------------------------------------------------
// zero workspace region (graph-capture-safe alternative to hipMemsetAsync)
// ---------------------------------------------------------------------------
__global__ void zero_kernel(float4* __restrict__ p, int n4) {
  int i = blockIdx.x * blockDim.x + threadIdx.x;
  int stride = gridDim.x * blockDim.x;
  float4 z = make_float4(0.f, 0.f, 0.f, 0.f);
  for (; i < n4; i += stride) p[i] = z;
}

// ---------------------------------------------------------------------------
// Edge MLP + in-tile segment max + global atomicMax scatter.
// One workgroup (256 thr) handles TE=64 consecutive edges.
//   h[e][j] = relu( concat(feats[nbr[e]], add_info[e]) . Wb[:,j] + bb[j] )
//   pooled[seg][j] = max over segment (segments sorted -> contiguous)
// relu >= 0 so uint-bitpattern atomicMax against 0-initialized pooled is
// exactly segment_max with empty segments -> 0.
// ---------------------------------------------------------------------------
__global__ __launch_bounds__(256) void edge_mlp_kernel(
    const float* __restrict__ feats, const float* __restrict__ add_info,
    const int* __restrict__ nbr, const int* __restrict__ segs,
    const float* __restrict__ Wb, const float* __restrict__ bb,
    float* __restrict__ pooled, int E)
{
  __shared__ float ef[TE][132];   // edge features (D=128 + A=4); 33.8 KB
  __shared__ int seg_l[TE];
  __shared__ int nbr_l[TE];
  __shared__ int rank_l[TE];
  __shared__ int segof[TE];
  __shared__ int ndist;

  const int tid = threadIdx.x;
  const int e0 = blockIdx.x * TE;

  if (tid < TE) {
    int e = e0 + tid;
    seg_l[tid] = (e < E) ? segs[e] : INT_MIN;
    nbr_l[tid] = (e < E) ? nbr[e] : 0;
  }
  __syncthreads();

  // local segment ranks (segments sorted => contiguous runs)
  if (tid < TE) {
    int r = 0;
    for (int i = 1; i <= tid; ++i) r += (seg_l[i] != seg_l[i - 1]) ? 1 : 0;
    rank_l[tid] = r;
    if (tid == 0 || seg_l[tid] != seg_l[tid - 1]) segof[r] = seg_l[tid];
    if (tid == TE - 1) ndist = r + 1;
  }

  // gather edge features: coalesced within each 128-float feats row
  for (int idx = tid; idx < TE * 132; idx += 256) {
    int e_l = idx / 132;
    int k = idx - e_l * 132;
    int e = e0 + e_l;
    float v = 0.f;
    if (e < E) {
      v = (k < 128) ? feats[(size_t)nbr_l[e_l] * 128 + k]
                    : add_info[(size_t)e * 4 + (k - 128)];
    }
    ef[e_l][k] = v;
  }
  __syncthreads();

  // 64x128 tile GEMM, K=132. Thread (te,tj): 4 edges x 8 outputs.
  const int te = tid >> 4;
  const int tj = tid & 15;
  const int jbase = tj * 8;

  float acc[4][8];
  #pragma unroll
  for (int i = 0; i < 4; ++i)
    #pragma unroll
    for (int u = 0; u < 8; ++u) acc[i][u] = 0.f;

  for (int k = 0; k < 132; k += 4) {
    float4 a[4];
    #pragma unroll
    for (int i = 0; i < 4; ++i)
      a[i] = *reinterpret_cast<const float4*>(&ef[te * 4 + i][k]);
    #pragma unroll
    for (int kk = 0; kk < 4; ++kk) {
      const float4* wrow =
          reinterpret_cast<const float4*>(Wb + (size_t)(k + kk) * 128 + jbase);
      float4 b0 = wrow[0];
      float4 b1 = wrow[1];
      float bv[8] = {b0.x, b0.y, b0.z, b0.w, b1.x, b1.y, b1.z, b1.w};
      #pragma unroll
      for (int i = 0; i < 4; ++i) {
        float av = (kk == 0) ? a[i].x : (kk == 1) ? a[i].y : (kk == 2) ? a[i].z : a[i].w;
        #pragma unroll
        for (int u = 0; u < 8; ++u) acc[i][u] += av * bv[u];
      }
    }
  }

  float bbv[8];
  #pragma unroll
  for (int u = 0; u < 8; ++u) bbv[u] = bb[jbase + u];

  __syncthreads();  // done reading ef -> reuse as reduce buffer (8192 uints)
  unsigned* red = reinterpret_cast<unsigned*>(&ef[0][0]);
  for (int idx = tid; idx < TE * 128; idx += 256) red[idx] = 0u;
  __syncthreads();

  #pragma unroll
  for (int i = 0; i < 4; ++i) {
    int e_l = te * 4 + i;
    if (e0 + e_l < E) {
      int r = rank_l[e_l];
      #pragma unroll
      for (int u = 0; u < 8; ++u) {
        float v = fmaxf(acc[i][u] + bbv[u], 0.f);
        atomicMax(&red[r * 128 + jbase + u], __float_as_uint(v));
      }
    }
  }
  __syncthreads();

  // one global atomic per (distinct segment, j); skip zeros (pooled is 0-init)
  int nd = ndist;
  for (int idx = tid; idx < nd * 128; idx += 256) {
    int d = idx >> 7;
    int j = idx & 127;
    int s = segof[d];
    unsigned v = red[idx];
    if (v != 0u && s >= 0)
      atomicMax(reinterpret_cast<unsigned*>(&pooled[(size_t)s * 128 + j]), v);
  }
}

// ---------------------------------------------------------------------------
// featsOut = featsIn + pooled @ Wo + bo   (N x 128, K=128)
// ---------------------------------------------------------------------------
__global__ __launch_bounds__(256) void update_kernel(
    const float* __restrict__ featsIn, const float* __restrict__ pooled,
    const float* __restrict__ Wo, const float* __restrict__ bo,
    float* __restrict__ featsOut, int N)
{
  __shared__ float pt[TE][132];  // padded to 132 to break 4-way LDS bank conflicts
  const int tid = threadIdx.x;
  const int n0 = blockIdx.x * TE;

  for (int idx = tid; idx < TE * 128; idx += 256) {
    int rl = idx >> 7, c = idx & 127;
    int n = n0 + rl;
    pt[rl][c] = (n < N) ? pooled[(size_t)n * 128 + c] : 0.f;
  }
  __syncthreads();

  const int te = tid >> 4;
  const int tj = tid & 15;
  const int jbase = tj * 8;

  float acc[4][8];
  #pragma unroll
  for (int i = 0; i < 4; ++i)
    #pragma unroll
    for (int u = 0; u < 8; ++u) acc[i][u] = 0.f;

  for (int k = 0; k < 128; k += 4) {
    float4 a[4];
    #pragma unroll
    for (int i = 0; i < 4; ++i)
      a[i] = *reinterpret_cast<const float4*>(&pt[te * 4 + i][k]);
    #pragma unroll
    for (int kk = 0; kk < 4; ++kk) {
      const float4* wrow =
          reinterpret_cast<const float4*>(Wo + (size_t)(k + kk) * 128 + jbase);
      float4 b0 = wrow[0];
      float4 b1 = wrow[1];
      float bv[8] = {b0.x, b0.y, b0.z, b0.w, b1.x, b1.y, b1.z, b1.w};
      #pragma unroll
      for (int i = 0; i < 4; ++i) {
        float av = (kk == 0) ? a[i].x : (kk == 1) ? a[i].y : (kk == 2) ? a[i].z : a[i].w;
        #pragma unroll
        for (int u = 0; u < 8; ++u) acc[i][u] += av * bv[u];
      }
    }
  }

  float bov[8];
  #pragma unroll
  for (int u = 0; u < 8; ++u) bov[u] = bo[jbase + u];

  #pragma unroll
  for (int i = 0; i < 4; ++i) {
    int n = n0 + te * 4 + i;
    if (n < N) {
      const float4* fin = reinterpret_cast<const float4*>(featsIn + (size_t)n * 128 + jbase);
      float4* fout = reinterpret_cast<float4*>(featsOut + (size_t)n * 128 + jbase);
      float4 r0 = fin[0], r1 = fin[1];
      float4 o0, o1;
      o0.x = r0.x + acc[i][0] + bov[0];
      o0.y = r0.y + acc[i][1] + bov[1];
      o0.z = r0.z + acc[i][2] + bov[2];
      o0.w = r0.w + acc[i][3] + bov[3];
      o1.x = r1.x + acc[i][4] + bov[4];
      o1.y = r1.y + acc[i][5] + bov[5];
      o1.z = r1.z + acc[i][6] + bov[6];
      o1.w = r1.w + acc[i][7] + bov[7];
      fout[0] = o0;
      fout[1] = o1;
    }
  }
}

// ---------------------------------------------------------------------------
// out[n] = x[n,:] . Wf + bf   (one wave per row, shuffle reduce)
// ---------------------------------------------------------------------------
__global__ __launch_bounds__(256) void final_kernel(
    const float* __restrict__ x, const float* __restrict__ Wf,
    const float* __restrict__ bf, float* __restrict__ out, int N)
{
  int gtid = blockIdx.x * blockDim.x + threadIdx.x;
  int wave = gtid >> 6;
  int lane = threadIdx.x & 63;
  int nw = (gridDim.x * blockDim.x) >> 6;
  float w0 = Wf[lane], w1 = Wf[64 + lane];
  float b0 = bf[0];
  for (int n = wave; n < N; n += nw) {
    const float* row = x + (size_t)n * 128;
    float v = row[lane] * w0 + row[64 + lane] * w1;
    #pragma unroll
    for (int off = 32; off > 0; off >>= 1) v += __shfl_down(v, off);
    if (lane == 0) out[n] = v + b0;
  }
}

// ---------------------------------------------------------------------------
extern "C" void kernel_launch(void* const* d_in, const int* in_sizes, int n_in,
                              void* d_out, int out_size, void* d_ws, size_t ws_size,
                              hipStream_t stream)
{
  const float* interpolated = (const float*)d_in[0];
  const float* add_info     = (const float*)d_in[1];
  const int*   nbr          = (const int*)d_in[2];
  const int*   segs         = (const int*)d_in[3];
  const float* Wb0 = (const float*)d_in[4];
  const float* bb0 = (const float*)d_in[5];
  const float* Wo0 = (const float*)d_in[6];
  const float* bo0 = (const float*)d_in[7];
  const float* Wb1 = (const float*)d_in[8];
  const float* bb1 = (const float*)d_in[9];
  const float* Wo1 = (const float*)d_in[10];
  const float* bo1 = (const float*)d_in[11];
  const float* Wf  = (const float*)d_in[12];
  const float* bf  = (const float*)d_in[13];

  const int N = in_sizes[0] / 128;
  const int E = in_sizes[2];
  float* out = (float*)d_out;

  // workspace: pooled (N*128 f32) | featsB (N*128 f32)  => 51.2 MB total
  float* pooled = (float*)d_ws;
  float* featsB = pooled + (size_t)N * 128;

  const int egrid = (E + TE - 1) / TE;
  const int ngrid = (N + TE - 1) / TE;
  const int zn4 = (N * 128) / 4;

  // block 0
  zero_kernel<<<1024, 256, 0, stream>>>((float4*)pooled, zn4);
  edge_mlp_kernel<<<egrid, 256, 0, stream>>>(interpolated, add_info, nbr, segs,
                                             Wb0, bb0, pooled, E);
  update_kernel<<<ngrid, 256, 0, stream>>>(interpolated, pooled, Wo0, bo0, featsB, N);

  // block 1
  zero_kernel<<<1024, 256, 0, stream>>>((float4*)pooled, zn4);
  edge_mlp_kernel<<<egrid, 256, 0, stream>>>(featsB, add_info, nbr, segs,
                                             Wb1, bb1, pooled, E);
  update_kernel<<<ngrid, 256, 0, stream>>>(featsB, pooled, Wo1, bo1, featsB, N);

  // final projection
  final_kernel<<<512, 256, 0, stream>>>(featsB, Wf, bf, out, N);
}

// Round 2
// 744.846 us; speedup vs baseline: 2.7948x; 2.7948x over previous
//
#include <hip/hip_runtime.h>
#include <limits.h>
#include <cstdint>

typedef __bf16 bf16_t;
typedef __attribute__((ext_vector_type(8))) __bf16 bf16x8;
typedef __attribute__((ext_vector_type(4))) float f32x4;

#define TE 64     // tile for fp32 update kernel
#define TEB 128   // edges per workgroup in MFMA edge kernel

// ---------------------------------------------------------------------------
// zero workspace region (graph-capture-safe)
// ---------------------------------------------------------------------------
__global__ void zero_kernel(float4* __restrict__ p, int n4) {
  int i = blockIdx.x * blockDim.x + threadIdx.x;
  int stride = gridDim.x * blockDim.x;
  float4 z = make_float4(0.f, 0.f, 0.f, 0.f);
  for (; i < n4; i += stride) p[i] = z;
}

// ---------------------------------------------------------------------------
// fp32 -> bf16 convert (RNE), 4 elems/thread
// ---------------------------------------------------------------------------
__global__ void convert_bf16_kernel(const float* __restrict__ in,
                                    bf16_t* __restrict__ out, int n) {
  int i = (blockIdx.x * blockDim.x + threadIdx.x) * 4;
  if (i < n) {
    float4 v = *reinterpret_cast<const float4*>(in + i);
    bf16_t o0 = (bf16_t)v.x, o1 = (bf16_t)v.y, o2 = (bf16_t)v.z, o3 = (bf16_t)v.w;
    ushort4 u;
    u.x = __builtin_bit_cast(unsigned short, o0);
    u.y = __builtin_bit_cast(unsigned short, o1);
    u.z = __builtin_bit_cast(unsigned short, o2);
    u.w = __builtin_bit_cast(unsigned short, o3);
    *reinterpret_cast<ushort4*>(out + i) = u;
  }
}

// ---------------------------------------------------------------------------
// Pack Wb (132 x 128 fp32) into MFMA B-fragment order, bf16, K padded to 160.
// packed[((kt*8 + nt)*64 + lane)*8 + j] = Wb[kt*32 + (lane>>4)*8 + j][nt*16 + (lane&15)]
// ---------------------------------------------------------------------------
__global__ void pack_wb_kernel(const float* __restrict__ Wb,
                               bf16_t* __restrict__ packed) {
  int idx = blockIdx.x * blockDim.x + threadIdx.x;   // 5*8*64*8 = 20480
  if (idx >= 5 * 8 * 64 * 8) return;
  int j  = idx & 7;
  int L  = (idx >> 3) & 63;
  int nt = (idx >> 9) & 7;
  int kt = idx >> 12;
  int k = kt * 32 + (L >> 4) * 8 + j;
  int n = nt * 16 + (L & 15);
  float v = (k < 132) ? Wb[(size_t)k * 128 + n] : 0.f;
  packed[idx] = (bf16_t)v;
}

// ---------------------------------------------------------------------------
// Edge MLP via bf16 MFMA + segment max.
// 256 thr = 4 waves; workgroup = 128 consecutive edges; wave w: edges
// [w*32, w*32+32) as 2 m-tiles x 8 n-tiles of 16x16x32 MFMA, K = 5 steps
// (4 from gathered feats, 1 from add_info zero-padded).
// A-frag gathered DIRECTLY from global: lane needs feats[nbr[e]][kt*32+q*8..+7]
// = one contiguous 16B load. Then relu+bias, run-length in-reg segment reduce,
// LDS atomicMax, one global atomicMax per (distinct segment, col).
// ---------------------------------------------------------------------------
__global__ __launch_bounds__(256) void edge_mlp_mfma(
    const bf16_t* __restrict__ featsb,   // N x 128 bf16
    const float* __restrict__ add_info,  // E x 4
    const int* __restrict__ nbr, const int* __restrict__ segs,
    const bf16_t* __restrict__ Wpk,      // packed 5*8*64*8 bf16
    const float* __restrict__ bb,
    float* __restrict__ pooled, int E)
{
  __shared__ unsigned red[TEB * 128];    // 64 KB reduce buffer
  __shared__ int seg_l[TEB];
  __shared__ int nbr_l[TEB];
  __shared__ int rank_l[TEB];
  __shared__ int segof[TEB];
  __shared__ int ndist;
  __shared__ int wave_carry;

  const int tid  = threadIdx.x;
  const int e0   = blockIdx.x * TEB;
  const int lane = tid & 63;
  const int w    = tid >> 6;      // wave 0..3
  const int q    = lane >> 4;     // quad 0..3
  const int ln   = lane & 15;

  if (tid < TEB) {
    int e = e0 + tid;
    seg_l[tid] = (e < E) ? segs[e] : INT_MIN;
    nbr_l[tid] = (e < E) ? nbr[e] : 0;
  }
  for (int i = tid; i < TEB * 128; i += 256) red[i] = 0u;
  __syncthreads();

  // segment ranks via per-wave ballot scan (segments sorted -> contiguous)
  int flag = 0, rank_partial = 0;
  if (tid < TEB) {
    flag = (tid > 0) && (seg_l[tid] != seg_l[tid - 1]);
    unsigned long long b = __ballot(flag);
    if (w == 0 && lane == 63) wave_carry = __popcll(b);
    rank_partial = __popcll(b & (~0ull >> (63 - lane)));  // bits 0..lane incl
  }
  __syncthreads();
  if (tid < TEB) {
    int r = rank_partial + ((w == 1) ? wave_carry : 0);
    rank_l[tid] = r;
    if (flag || tid == 0) segof[r] = seg_l[tid];
    if (tid == TEB - 1) ndist = r + 1;
  }
  __syncthreads();

  // ---- MFMA compute ----
  const int ebase = w * 32;
  const int erow0 = ebase + ln;        // edge-local for m-tile 0, row ln
  const int erow1 = ebase + 16 + ln;   // m-tile 1
  const bf16_t* aptr0 = featsb + (size_t)nbr_l[erow0] * 128 + q * 8;
  const bf16_t* aptr1 = featsb + (size_t)nbr_l[erow1] * 128 + q * 8;

  f32x4 acc[2][8];
  #pragma unroll
  for (int mt = 0; mt < 2; ++mt)
    #pragma unroll
    for (int nt = 0; nt < 8; ++nt)
      #pragma unroll
      for (int r = 0; r < 4; ++r) acc[mt][nt][r] = 0.f;

  const bf16x8* Wp = reinterpret_cast<const bf16x8*>(Wpk);

  #pragma unroll
  for (int kt = 0; kt < 4; ++kt) {
    bf16x8 a0 = *reinterpret_cast<const bf16x8*>(aptr0 + kt * 32);
    bf16x8 a1 = *reinterpret_cast<const bf16x8*>(aptr1 + kt * 32);
    #pragma unroll
    for (int nt = 0; nt < 8; ++nt) {
      bf16x8 bfrag = Wp[(kt * 8 + nt) * 64 + lane];
      acc[0][nt] = __builtin_amdgcn_mfma_f32_16x16x32_bf16(a0, bfrag, acc[0][nt], 0, 0, 0);
      acc[1][nt] = __builtin_amdgcn_mfma_f32_16x16x32_bf16(a1, bfrag, acc[1][nt], 0, 0, 0);
    }
  }
  // kt = 4: K rows 128..131 = add_info, 132..159 = 0
  {
    bf16x8 a0, a1;
    #pragma unroll
    for (int j = 0; j < 8; ++j) { a0[j] = (bf16_t)0.f; a1[j] = (bf16_t)0.f; }
    if (q == 0) {
      int eg0 = e0 + erow0;
      int eg1 = e0 + erow1;
      if (eg0 < E) {
        float4 ai = *reinterpret_cast<const float4*>(add_info + (size_t)eg0 * 4);
        a0[0] = (bf16_t)ai.x; a0[1] = (bf16_t)ai.y; a0[2] = (bf16_t)ai.z; a0[3] = (bf16_t)ai.w;
      }
      if (eg1 < E) {
        float4 ai = *reinterpret_cast<const float4*>(add_info + (size_t)eg1 * 4);
        a1[0] = (bf16_t)ai.x; a1[1] = (bf16_t)ai.y; a1[2] = (bf16_t)ai.z; a1[3] = (bf16_t)ai.w;
      }
    }
    #pragma unroll
    for (int nt = 0; nt < 8; ++nt) {
      bf16x8 bfrag = Wp[(4 * 8 + nt) * 64 + lane];
      acc[0][nt] = __builtin_amdgcn_mfma_f32_16x16x32_bf16(a0, bfrag, acc[0][nt], 0, 0, 0);
      acc[1][nt] = __builtin_amdgcn_mfma_f32_16x16x32_bf16(a1, bfrag, acc[1][nt], 0, 0, 0);
    }
  }

  // bias per lane: col j = nt*16 + ln
  float bbv[8];
  #pragma unroll
  for (int nt = 0; nt < 8; ++nt) bbv[nt] = bb[nt * 16 + ln];

  // ---- in-register run-length reduce, then LDS atomicMax ----
  // C layout: col = lane&15, row = q*4 + r  -> edge-local = ebase + mt*16 + q*4 + r
  #pragma unroll
  for (int mt = 0; mt < 2; ++mt) {
    int rowb = ebase + mt * 16 + q * 4;
    #pragma unroll
    for (int nt = 0; nt < 8; ++nt) {
      int col = nt * 16 + ln;
      float vmax = 0.f;
      int prev_rank = -1;
      #pragma unroll
      for (int r = 0; r < 4; ++r) {
        int el = rowb + r;
        float v = fmaxf(acc[mt][nt][r] + bbv[nt], 0.f);
        int rk = rank_l[el];
        if (rk == prev_rank) {
          vmax = fmaxf(vmax, v);
        } else {
          if (prev_rank >= 0)
            atomicMax(&red[prev_rank * 128 + col], __float_as_uint(vmax));
          prev_rank = rk;
          vmax = v;
        }
      }
      atomicMax(&red[prev_rank * 128 + col], __float_as_uint(vmax));
    }
  }
  __syncthreads();

  // one global atomic per (distinct segment, col); skip zeros (pooled 0-init)
  int nd = ndist;
  for (int idx = tid; idx < nd * 128; idx += 256) {
    int d = idx >> 7;
    int j = idx & 127;
    int s = segof[d];
    unsigned v = red[idx];
    if (v != 0u && s != INT_MIN)
      atomicMax(reinterpret_cast<unsigned*>(&pooled[(size_t)s * 128 + j]), v);
  }
}

// ---------------------------------------------------------------------------
// featsOut = featsIn + pooled @ Wo + bo  (fp32); also emits bf16 copy for the
// next block's gather.
// ---------------------------------------------------------------------------
__global__ __launch_bounds__(256) void update_kernel(
    const float* __restrict__ featsIn, const float* __restrict__ pooled,
    const float* __restrict__ Wo, const float* __restrict__ bo,
    float* __restrict__ featsOut, bf16_t* __restrict__ featsOutBf, int N)
{
  __shared__ float pt[TE][132];
  const int tid = threadIdx.x;
  const int n0 = blockIdx.x * TE;

  for (int idx = tid; idx < TE * 128; idx += 256) {
    int rl = idx >> 7, c = idx & 127;
    int n = n0 + rl;
    pt[rl][c] = (n < N) ? pooled[(size_t)n * 128 + c] : 0.f;
  }
  __syncthreads();

  const int te = tid >> 4;
  const int tj = tid & 15;
  const int jbase = tj * 8;

  float acc[4][8];
  #pragma unroll
  for (int i = 0; i < 4; ++i)
    #pragma unroll
    for (int u = 0; u < 8; ++u) acc[i][u] = 0.f;

  for (int k = 0; k < 128; k += 4) {
    float4 a[4];
    #pragma unroll
    for (int i = 0; i < 4; ++i)
      a[i] = *reinterpret_cast<const float4*>(&pt[te * 4 + i][k]);
    #pragma unroll
    for (int kk = 0; kk < 4; ++kk) {
      const float4* wrow =
          reinterpret_cast<const float4*>(Wo + (size_t)(k + kk) * 128 + jbase);
      float4 b0 = wrow[0];
      float4 b1 = wrow[1];
      float bv[8] = {b0.x, b0.y, b0.z, b0.w, b1.x, b1.y, b1.z, b1.w};
      #pragma unroll
      for (int i = 0; i < 4; ++i) {
        float av = (kk == 0) ? a[i].x : (kk == 1) ? a[i].y : (kk == 2) ? a[i].z : a[i].w;
        #pragma unroll
        for (int u = 0; u < 8; ++u) acc[i][u] += av * bv[u];
      }
    }
  }

  float bov[8];
  #pragma unroll
  for (int u = 0; u < 8; ++u) bov[u] = bo[jbase + u];

  #pragma unroll
  for (int i = 0; i < 4; ++i) {
    int n = n0 + te * 4 + i;
    if (n < N) {
      const float4* fin = reinterpret_cast<const float4*>(featsIn + (size_t)n * 128 + jbase);
      float4* fout = reinterpret_cast<float4*>(featsOut + (size_t)n * 128 + jbase);
      float4 r0 = fin[0], r1 = fin[1];
      float o[8];
      o[0] = r0.x + acc[i][0] + bov[0];
      o[1] = r0.y + acc[i][1] + bov[1];
      o[2] = r0.z + acc[i][2] + bov[2];
      o[3] = r0.w + acc[i][3] + bov[3];
      o[4] = r1.x + acc[i][4] + bov[4];
      o[5] = r1.y + acc[i][5] + bov[5];
      o[6] = r1.z + acc[i][6] + bov[6];
      o[7] = r1.w + acc[i][7] + bov[7];
      float4 o0 = make_float4(o[0], o[1], o[2], o[3]);
      float4 o1 = make_float4(o[4], o[5], o[6], o[7]);
      fout[0] = o0;
      fout[1] = o1;
      // bf16 copy for next gather
      ushort4 u0, u1;
      bf16_t b0a = (bf16_t)o[0], b1a = (bf16_t)o[1], b2a = (bf16_t)o[2], b3a = (bf16_t)o[3];
      bf16_t b4a = (bf16_t)o[4], b5a = (bf16_t)o[5], b6a = (bf16_t)o[6], b7a = (bf16_t)o[7];
      u0.x = __builtin_bit_cast(unsigned short, b0a);
      u0.y = __builtin_bit_cast(unsigned short, b1a);
      u0.z = __builtin_bit_cast(unsigned short, b2a);
      u0.w = __builtin_bit_cast(unsigned short, b3a);
      u1.x = __builtin_bit_cast(unsigned short, b4a);
      u1.y = __builtin_bit_cast(unsigned short, b5a);
      u1.z = __builtin_bit_cast(unsigned short, b6a);
      u1.w = __builtin_bit_cast(unsigned short, b7a);
      ushort4* bout = reinterpret_cast<ushort4*>(featsOutBf + (size_t)n * 128 + jbase);
      bout[0] = u0;
      bout[1] = u1;
    }
  }
}

// ---------------------------------------------------------------------------
// out[n] = x[n,:] . Wf + bf
// ---------------------------------------------------------------------------
__global__ __launch_bounds__(256) void final_kernel(
    const float* __restrict__ x, const float* __restrict__ Wf,
    const float* __restrict__ bf, float* __restrict__ out, int N)
{
  int gtid = blockIdx.x * blockDim.x + threadIdx.x;
  int wave = gtid >> 6;
  int lane = threadIdx.x & 63;
  int nw = (gridDim.x * blockDim.x) >> 6;
  float w0 = Wf[lane], w1 = Wf[64 + lane];
  float b0 = bf[0];
  for (int n = wave; n < N; n += nw) {
    const float* row = x + (size_t)n * 128;
    float v = row[lane] * w0 + row[64 + lane] * w1;
    #pragma unroll
    for (int off = 32; off > 0; off >>= 1) v += __shfl_down(v, off);
    if (lane == 0) out[n] = v + b0;
  }
}

// ---------------------------------------------------------------------------
extern "C" void kernel_launch(void* const* d_in, const int* in_sizes, int n_in,
                              void* d_out, int out_size, void* d_ws, size_t ws_size,
                              hipStream_t stream)
{
  const float* interpolated = (const float*)d_in[0];
  const float* add_info     = (const float*)d_in[1];
  const int*   nbr          = (const int*)d_in[2];
  const int*   segs         = (const int*)d_in[3];
  const float* Wb0 = (const float*)d_in[4];
  const float* bb0 = (const float*)d_in[5];
  const float* Wo0 = (const float*)d_in[6];
  const float* bo0 = (const float*)d_in[7];
  const float* Wb1 = (const float*)d_in[8];
  const float* bb1 = (const float*)d_in[9];
  const float* Wo1 = (const float*)d_in[10];
  const float* bo1 = (const float*)d_in[11];
  const float* Wf  = (const float*)d_in[12];
  const float* bf  = (const float*)d_in[13];

  const int N = in_sizes[0] / 128;
  const int E = in_sizes[2];
  float* out = (float*)d_out;

  // workspace layout
  float* pooled = (float*)d_ws;                         // N*128 f32
  float* featsB = pooled + (size_t)N * 128;             // N*128 f32
  bf16_t* featsA_bf = (bf16_t*)(featsB + (size_t)N * 128);  // N*128 bf16
  bf16_t* featsB_bf = featsA_bf + (size_t)N * 128;          // N*128 bf16
  bf16_t* Wpk0 = featsB_bf + (size_t)N * 128;               // 20480 bf16
  bf16_t* Wpk1 = Wpk0 + 5 * 8 * 64 * 8;                     // 20480 bf16

  const int egrid = (E + TEB - 1) / TEB;
  const int ngrid = (N + TE - 1) / TE;
  const int zn4 = (N * 128) / 4;
  const int cgrid = ((N * 128) / 4 + 255) / 256;

  // prep: pack weights, convert feats to bf16
  pack_wb_kernel<<<80, 256, 0, stream>>>(Wb0, Wpk0);
  pack_wb_kernel<<<80, 256, 0, stream>>>(Wb1, Wpk1);
  convert_bf16_kernel<<<cgrid, 256, 0, stream>>>(interpolated, featsA_bf, N * 128);

  // block 0
  zero_kernel<<<1024, 256, 0, stream>>>((float4*)pooled, zn4);
  edge_mlp_mfma<<<egrid, 256, 0, stream>>>(featsA_bf, add_info, nbr, segs,
                                           Wpk0, bb0, pooled, E);
  update_kernel<<<ngrid, 256, 0, stream>>>(interpolated, pooled, Wo0, bo0,
                                           featsB, featsB_bf, N);

  // block 1
  zero_kernel<<<1024, 256, 0, stream>>>((float4*)pooled, zn4);
  edge_mlp_mfma<<<egrid, 256, 0, stream>>>(featsB_bf, add_info, nbr, segs,
                                           Wpk1, bb1, pooled, E);
  update_kernel<<<ngrid, 256, 0, stream>>>(featsB, pooled, Wo1, bo1,
                                           featsB, featsA_bf, N);

  // final projection
  final_kernel<<<512, 256, 0, stream>>>(featsB, Wf, bf, out, N);
}

// Round 3
// 540.500 us; speedup vs baseline: 3.8514x; 1.3781x over previous
//
#include <hip/hip_runtime.h>
#include <limits.h>
#include <cstdint>

typedef __bf16 bf16_t;
typedef __attribute__((ext_vector_type(8))) __bf16 bf16x8;
typedef __attribute__((ext_vector_type(4))) float f32x4;

#define TEB 128   // edges per workgroup in MFMA edge kernel
#define RMAX 64   // LDS rank-reduce slots (expected ndist ~5; fallback covers rest)

// ---------------------------------------------------------------------------
__global__ void zero_kernel(float4* __restrict__ p, int n4) {
  int i = blockIdx.x * blockDim.x + threadIdx.x;
  int stride = gridDim.x * blockDim.x;
  float4 z = make_float4(0.f, 0.f, 0.f, 0.f);
  for (; i < n4; i += stride) p[i] = z;
}

// ---------------------------------------------------------------------------
__global__ void convert_bf16_kernel(const float* __restrict__ in,
                                    bf16_t* __restrict__ out, int n) {
  int i = (blockIdx.x * blockDim.x + threadIdx.x) * 4;
  if (i < n) {
    float4 v = *reinterpret_cast<const float4*>(in + i);
    bf16_t o0 = (bf16_t)v.x, o1 = (bf16_t)v.y, o2 = (bf16_t)v.z, o3 = (bf16_t)v.w;
    ushort4 u;
    u.x = __builtin_bit_cast(unsigned short, o0);
    u.y = __builtin_bit_cast(unsigned short, o1);
    u.z = __builtin_bit_cast(unsigned short, o2);
    u.w = __builtin_bit_cast(unsigned short, o3);
    *reinterpret_cast<ushort4*>(out + i) = u;
  }
}

// ---------------------------------------------------------------------------
// Pack W (KROWS x 128 fp32) into MFMA B-fragment order, bf16, K padded to
// KTILES*32. packed[((kt*8+nt)*64+L)*8+j] = W[kt*32+(L>>4)*8+j][nt*16+(L&15)]
// ---------------------------------------------------------------------------
__global__ void pack_w_kernel(const float* __restrict__ W,
                              bf16_t* __restrict__ packed, int KROWS, int KTILES) {
  int idx = blockIdx.x * blockDim.x + threadIdx.x;
  if (idx >= KTILES * 8 * 64 * 8) return;
  int j  = idx & 7;
  int L  = (idx >> 3) & 63;
  int nt = (idx >> 9) & 7;
  int kt = idx >> 12;
  int k = kt * 32 + (L >> 4) * 8 + j;
  int n = nt * 16 + (L & 15);
  float v = (k < KROWS) ? W[(size_t)k * 128 + n] : 0.f;
  packed[idx] = (bf16_t)v;
}

// ---------------------------------------------------------------------------
// Edge MLP via bf16 MFMA + segment max. 4 waves x 32 edges = 128 edges/WG.
// LDS reduce buffer shrunk to RMAX=64 ranks (34 KB total -> 4 blocks/CU);
// ranks >= RMAX fall back to direct global atomicMax (rare).
// ---------------------------------------------------------------------------
__global__ __launch_bounds__(256, 4) void edge_mlp_mfma(
    const bf16_t* __restrict__ featsb,   // N x 128 bf16
    const float* __restrict__ add_info,  // E x 4
    const int* __restrict__ nbr, const int* __restrict__ segs,
    const bf16_t* __restrict__ Wpk,      // packed 5*8*64*8 bf16
    const float* __restrict__ bb,
    float* __restrict__ pooled, int E)
{
  __shared__ unsigned red[RMAX * 128];   // 32 KB
  __shared__ int seg_l[TEB];
  __shared__ int rank_l[TEB];
  __shared__ int segof[TEB];
  __shared__ int ndist;
  __shared__ int wave_carry;

  const int tid  = threadIdx.x;
  const int e0   = blockIdx.x * TEB;
  const int lane = tid & 63;
  const int w    = tid >> 6;      // wave 0..3
  const int q    = lane >> 4;     // quad 0..3
  const int ln   = lane & 15;

  // per-thread edge rows (m-tiles) and direct nbr loads (no LDS dependency)
  const int ebase = w * 32;
  const int erow0 = ebase + ln;
  const int erow1 = ebase + 16 + ln;
  const int eg0 = e0 + erow0;
  const int eg1 = e0 + erow1;
  const int nb0 = (eg0 < E) ? nbr[eg0] : 0;
  const int nb1 = (eg1 < E) ? nbr[eg1] : 0;

  if (tid < TEB) {
    int e = e0 + tid;
    seg_l[tid] = (e < E) ? segs[e] : INT_MIN;
  }
  for (int i = tid; i < RMAX * 128; i += 256) red[i] = 0u;
  __syncthreads();

  // segment ranks via ballot scan (segments sorted -> contiguous runs)
  int flag = 0, rank_partial = 0;
  if (tid < TEB) {
    flag = (tid > 0) && (seg_l[tid] != seg_l[tid - 1]);
    unsigned long long b = __ballot(flag);
    if (w == 0 && lane == 63) wave_carry = __popcll(b);
    rank_partial = __popcll(b & (~0ull >> (63 - lane)));
  }
  __syncthreads();
  if (tid < TEB) {
    int r = rank_partial + ((w == 1) ? wave_carry : 0);
    rank_l[tid] = r;
    if (flag || tid == 0) segof[r] = seg_l[tid];
    if (tid == TEB - 1) ndist = r + 1;
  }
  __syncthreads();

  // ---- prefetch all A-frags (8 x 16B gathers) + add_info up front ----
  const bf16_t* aptr0 = featsb + (size_t)nb0 * 128 + q * 8;
  const bf16_t* aptr1 = featsb + (size_t)nb1 * 128 + q * 8;
  bf16x8 a0[4], a1[4];
  #pragma unroll
  for (int kt = 0; kt < 4; ++kt) {
    a0[kt] = *reinterpret_cast<const bf16x8*>(aptr0 + kt * 32);
    a1[kt] = *reinterpret_cast<const bf16x8*>(aptr1 + kt * 32);
  }
  bf16x8 ax0, ax1;
  #pragma unroll
  for (int j = 0; j < 8; ++j) { ax0[j] = (bf16_t)0.f; ax1[j] = (bf16_t)0.f; }
  if (q == 0) {
    if (eg0 < E) {
      float4 ai = *reinterpret_cast<const float4*>(add_info + (size_t)eg0 * 4);
      ax0[0] = (bf16_t)ai.x; ax0[1] = (bf16_t)ai.y; ax0[2] = (bf16_t)ai.z; ax0[3] = (bf16_t)ai.w;
    }
    if (eg1 < E) {
      float4 ai = *reinterpret_cast<const float4*>(add_info + (size_t)eg1 * 4);
      ax1[0] = (bf16_t)ai.x; ax1[1] = (bf16_t)ai.y; ax1[2] = (bf16_t)ai.z; ax1[3] = (bf16_t)ai.w;
    }
  }

  f32x4 acc[2][8];
  #pragma unroll
  for (int mt = 0; mt < 2; ++mt)
    #pragma unroll
    for (int nt = 0; nt < 8; ++nt)
      #pragma unroll
      for (int r = 0; r < 4; ++r) acc[mt][nt][r] = 0.f;

  const bf16x8* Wp = reinterpret_cast<const bf16x8*>(Wpk);

  #pragma unroll
  for (int kt = 0; kt < 4; ++kt) {
    #pragma unroll
    for (int nt = 0; nt < 8; ++nt) {
      bf16x8 bfrag = Wp[(kt * 8 + nt) * 64 + lane];
      acc[0][nt] = __builtin_amdgcn_mfma_f32_16x16x32_bf16(a0[kt], bfrag, acc[0][nt], 0, 0, 0);
      acc[1][nt] = __builtin_amdgcn_mfma_f32_16x16x32_bf16(a1[kt], bfrag, acc[1][nt], 0, 0, 0);
    }
  }
  #pragma unroll
  for (int nt = 0; nt < 8; ++nt) {
    bf16x8 bfrag = Wp[(4 * 8 + nt) * 64 + lane];
    acc[0][nt] = __builtin_amdgcn_mfma_f32_16x16x32_bf16(ax0, bfrag, acc[0][nt], 0, 0, 0);
    acc[1][nt] = __builtin_amdgcn_mfma_f32_16x16x32_bf16(ax1, bfrag, acc[1][nt], 0, 0, 0);
  }

  float bbv[8];
  #pragma unroll
  for (int nt = 0; nt < 8; ++nt) bbv[nt] = bb[nt * 16 + ln];

  // hoist the 8 ranks this thread owns (was 64 LDS reads inside nt loop)
  int rks[2][4];
  #pragma unroll
  for (int mt = 0; mt < 2; ++mt)
    #pragma unroll
    for (int r = 0; r < 4; ++r)
      rks[mt][r] = rank_l[ebase + mt * 16 + q * 4 + r];

  // in-register run-length reduce -> LDS atomicMax (rank<RMAX) or global
  #pragma unroll
  for (int mt = 0; mt < 2; ++mt) {
    int rowb = ebase + mt * 16 + q * 4;
    #pragma unroll
    for (int nt = 0; nt < 8; ++nt) {
      int col = nt * 16 + ln;
      float vmax = 0.f;
      int prev = -1, prev_el = 0;
      #pragma unroll
      for (int r = 0; r < 4; ++r) {
        float v = fmaxf(acc[mt][nt][r] + bbv[nt], 0.f);
        int rk = rks[mt][r];
        if (rk == prev) {
          vmax = fmaxf(vmax, v);
        } else {
          if (prev >= 0) {
            if (prev < RMAX) {
              atomicMax(&red[prev * 128 + col], __float_as_uint(vmax));
            } else {
              int s = seg_l[prev_el];
              if (s >= 0 && vmax > 0.f)
                atomicMax(reinterpret_cast<unsigned*>(&pooled[(size_t)s * 128 + col]),
                          __float_as_uint(vmax));
            }
          }
          prev = rk; prev_el = rowb + r; vmax = v;
        }
      }
      if (prev < RMAX) {
        atomicMax(&red[prev * 128 + col], __float_as_uint(vmax));
      } else {
        int s = seg_l[prev_el];
        if (s >= 0 && vmax > 0.f)
          atomicMax(reinterpret_cast<unsigned*>(&pooled[(size_t)s * 128 + col]),
                    __float_as_uint(vmax));
      }
    }
  }
  __syncthreads();

  // one global atomic per (distinct segment, col); skip zeros (pooled 0-init)
  int nd = ndist; if (nd > RMAX) nd = RMAX;
  for (int idx = tid; idx < nd * 128; idx += 256) {
    int d = idx >> 7;
    int j = idx & 127;
    int s = segof[d];
    unsigned v = red[idx];
    if (v != 0u && s != INT_MIN)
      atomicMax(reinterpret_cast<unsigned*>(&pooled[(size_t)s * 128 + j]), v);
  }
}

// ---------------------------------------------------------------------------
// featsOut = featsIn + pooled @ Wo + bo via bf16 MFMA (pooled converted
// in-flight). Optionally emits bf16 copy for the next block's gather.
// 4 waves x 32 rows = 128 rows per WG.
// ---------------------------------------------------------------------------
__global__ __launch_bounds__(256, 4) void update_mfma(
    const float* __restrict__ featsIn, const float* __restrict__ pooled,
    const bf16_t* __restrict__ Wopk,   // packed 4*8*64*8 bf16
    const float* __restrict__ bo,
    float* __restrict__ featsOut, bf16_t* __restrict__ featsOutBf, int N)
{
  const int tid  = threadIdx.x;
  const int lane = tid & 63;
  const int w    = tid >> 6;
  const int q    = lane >> 4;
  const int ln   = lane & 15;
  const int n0   = blockIdx.x * 128 + w * 32;

  int r0 = n0 + ln, r1 = n0 + 16 + ln;
  int r0c = (r0 < N) ? r0 : (N - 1);
  int r1c = (r1 < N) ? r1 : (N - 1);
  const float* p0 = pooled + (size_t)r0c * 128 + q * 8;
  const float* p1 = pooled + (size_t)r1c * 128 + q * 8;

  f32x4 acc[2][8];
  #pragma unroll
  for (int mt = 0; mt < 2; ++mt)
    #pragma unroll
    for (int nt = 0; nt < 8; ++nt)
      #pragma unroll
      for (int r = 0; r < 4; ++r) acc[mt][nt][r] = 0.f;

  const bf16x8* Wp = reinterpret_cast<const bf16x8*>(Wopk);

  #pragma unroll
  for (int kt = 0; kt < 4; ++kt) {
    float4 f0a = *reinterpret_cast<const float4*>(p0 + kt * 32);
    float4 f0b = *reinterpret_cast<const float4*>(p0 + kt * 32 + 4);
    float4 f1a = *reinterpret_cast<const float4*>(p1 + kt * 32);
    float4 f1b = *reinterpret_cast<const float4*>(p1 + kt * 32 + 4);
    bf16x8 a0, a1;
    a0[0] = (bf16_t)f0a.x; a0[1] = (bf16_t)f0a.y; a0[2] = (bf16_t)f0a.z; a0[3] = (bf16_t)f0a.w;
    a0[4] = (bf16_t)f0b.x; a0[5] = (bf16_t)f0b.y; a0[6] = (bf16_t)f0b.z; a0[7] = (bf16_t)f0b.w;
    a1[0] = (bf16_t)f1a.x; a1[1] = (bf16_t)f1a.y; a1[2] = (bf16_t)f1a.z; a1[3] = (bf16_t)f1a.w;
    a1[4] = (bf16_t)f1b.x; a1[5] = (bf16_t)f1b.y; a1[6] = (bf16_t)f1b.z; a1[7] = (bf16_t)f1b.w;
    #pragma unroll
    for (int nt = 0; nt < 8; ++nt) {
      bf16x8 bfrag = Wp[(kt * 8 + nt) * 64 + lane];
      acc[0][nt] = __builtin_amdgcn_mfma_f32_16x16x32_bf16(a0, bfrag, acc[0][nt], 0, 0, 0);
      acc[1][nt] = __builtin_amdgcn_mfma_f32_16x16x32_bf16(a1, bfrag, acc[1][nt], 0, 0, 0);
    }
  }

  float bov[8];
  #pragma unroll
  for (int nt = 0; nt < 8; ++nt) bov[nt] = bo[nt * 16 + ln];

  #pragma unroll
  for (int mt = 0; mt < 2; ++mt) {
    #pragma unroll
    for (int r = 0; r < 4; ++r) {
      int row = n0 + mt * 16 + q * 4 + r;
      if (row < N) {
        #pragma unroll
        for (int nt = 0; nt < 8; ++nt) {
          int col = nt * 16 + ln;
          float o = featsIn[(size_t)row * 128 + col] + acc[mt][nt][r] + bov[nt];
          featsOut[(size_t)row * 128 + col] = o;
          if (featsOutBf) {
            bf16_t ob = (bf16_t)o;
            featsOutBf[(size_t)row * 128 + col] = ob;
          }
        }
      }
    }
  }
}

// ---------------------------------------------------------------------------
__global__ __launch_bounds__(256) void final_kernel(
    const float* __restrict__ x, const float* __restrict__ Wf,
    const float* __restrict__ bf_, float* __restrict__ out, int N)
{
  int gtid = blockIdx.x * blockDim.x + threadIdx.x;
  int wave = gtid >> 6;
  int lane = threadIdx.x & 63;
  int nw = (gridDim.x * blockDim.x) >> 6;
  float w0 = Wf[lane], w1 = Wf[64 + lane];
  float b0 = bf_[0];
  for (int n = wave; n < N; n += nw) {
    const float* row = x + (size_t)n * 128;
    float v = row[lane] * w0 + row[64 + lane] * w1;
    #pragma unroll
    for (int off = 32; off > 0; off >>= 1) v += __shfl_down(v, off);
    if (lane == 0) out[n] = v + b0;
  }
}

// ---------------------------------------------------------------------------
extern "C" void kernel_launch(void* const* d_in, const int* in_sizes, int n_in,
                              void* d_out, int out_size, void* d_ws, size_t ws_size,
                              hipStream_t stream)
{
  const float* interpolated = (const float*)d_in[0];
  const float* add_info     = (const float*)d_in[1];
  const int*   nbr          = (const int*)d_in[2];
  const int*   segs         = (const int*)d_in[3];
  const float* Wb0 = (const float*)d_in[4];
  const float* bb0 = (const float*)d_in[5];
  const float* Wo0 = (const float*)d_in[6];
  const float* bo0 = (const float*)d_in[7];
  const float* Wb1 = (const float*)d_in[8];
  const float* bb1 = (const float*)d_in[9];
  const float* Wo1 = (const float*)d_in[10];
  const float* bo1 = (const float*)d_in[11];
  const float* Wf  = (const float*)d_in[12];
  const float* bf_ = (const float*)d_in[13];

  const int N = in_sizes[0] / 128;
  const int E = in_sizes[2];
  float* out = (float*)d_out;

  // workspace layout
  float* pooled = (float*)d_ws;                              // N*128 f32
  float* featsB = pooled + (size_t)N * 128;                  // N*128 f32
  bf16_t* featsA_bf = (bf16_t*)(featsB + (size_t)N * 128);   // N*128 bf16
  bf16_t* featsB_bf = featsA_bf + (size_t)N * 128;           // N*128 bf16
  bf16_t* Wpk0 = featsB_bf + (size_t)N * 128;                // 20480
  bf16_t* Wpk1 = Wpk0 + 5 * 8 * 64 * 8;                      // 20480
  bf16_t* Wopk0 = Wpk1 + 5 * 8 * 64 * 8;                     // 16384
  bf16_t* Wopk1 = Wopk0 + 4 * 8 * 64 * 8;                    // 16384

  const int egrid = (E + TEB - 1) / TEB;
  const int ugrid = (N + 127) / 128;
  const int zn4 = (N * 128) / 4;
  const int cgrid = ((N * 128) / 4 + 255) / 256;

  // prep
  pack_w_kernel<<<80, 256, 0, stream>>>(Wb0, Wpk0, 132, 5);
  pack_w_kernel<<<80, 256, 0, stream>>>(Wb1, Wpk1, 132, 5);
  pack_w_kernel<<<64, 256, 0, stream>>>(Wo0, Wopk0, 128, 4);
  pack_w_kernel<<<64, 256, 0, stream>>>(Wo1, Wopk1, 128, 4);
  convert_bf16_kernel<<<cgrid, 256, 0, stream>>>(interpolated, featsA_bf, N * 128);

  // block 0
  zero_kernel<<<1024, 256, 0, stream>>>((float4*)pooled, zn4);
  edge_mlp_mfma<<<egrid, 256, 0, stream>>>(featsA_bf, add_info, nbr, segs,
                                           Wpk0, bb0, pooled, E);
  update_mfma<<<ugrid, 256, 0, stream>>>(interpolated, pooled, Wopk0, bo0,
                                         featsB, featsB_bf, N);

  // block 1
  zero_kernel<<<1024, 256, 0, stream>>>((float4*)pooled, zn4);
  edge_mlp_mfma<<<egrid, 256, 0, stream>>>(featsB_bf, add_info, nbr, segs,
                                           Wpk1, bb1, pooled, E);
  update_mfma<<<ugrid, 256, 0, stream>>>(featsB, pooled, Wopk1, bo1,
                                         featsB, (bf16_t*)nullptr, N);

  // final projection
  final_kernel<<<512, 256, 0, stream>>>(featsB, Wf, bf_, out, N);
}

// Round 5
// 482.659 us; speedup vs baseline: 4.3129x; 1.1198x over previous
//
#include <hip/hip_runtime.h>
#include <limits.h>
#include <cstdint>

typedef __bf16 bf16_t;
typedef __attribute__((ext_vector_type(8))) __bf16 bf16x8;
typedef __attribute__((ext_vector_type(4))) float f32x4;

#define TEB 128   // edges per workgroup (4 waves x 32 edges)
#define RW 8      // per-wave LDS rank slots (ndist per 32 edges ~1-3; uniform fallback)

// ---------------------------------------------------------------------------
__global__ void zero_kernel(float4* __restrict__ p, int n4) {
  int i = blockIdx.x * blockDim.x + threadIdx.x;
  int stride = gridDim.x * blockDim.x;
  float4 z = make_float4(0.f, 0.f, 0.f, 0.f);
  for (; i < n4; i += stride) p[i] = z;
}

// ---------------------------------------------------------------------------
__global__ void convert_bf16_kernel(const float* __restrict__ in,
                                    bf16_t* __restrict__ out, int n) {
  int i = (blockIdx.x * blockDim.x + threadIdx.x) * 4;
  if (i < n) {
    float4 v = *reinterpret_cast<const float4*>(in + i);
    bf16_t o0 = (bf16_t)v.x, o1 = (bf16_t)v.y, o2 = (bf16_t)v.z, o3 = (bf16_t)v.w;
    ushort4 u;
    u.x = __builtin_bit_cast(unsigned short, o0);
    u.y = __builtin_bit_cast(unsigned short, o1);
    u.z = __builtin_bit_cast(unsigned short, o2);
    u.w = __builtin_bit_cast(unsigned short, o3);
    *reinterpret_cast<ushort4*>(out + i) = u;
  }
}

// ---------------------------------------------------------------------------
// Pack W (KROWS x 128 fp32) -> MFMA B-frag order, bf16, K padded to KTILES*32.
// packed[((kt*8+nt)*64+L)*8+j] = W[kt*32+(L>>4)*8+j][nt*16+(L&15)]
// ---------------------------------------------------------------------------
__global__ void pack_w_kernel(const float* __restrict__ W,
                              bf16_t* __restrict__ packed, int KROWS, int KTILES) {
  int idx = blockIdx.x * blockDim.x + threadIdx.x;
  if (idx >= KTILES * 8 * 64 * 8) return;
  int j  = idx & 7;
  int L  = (idx >> 3) & 63;
  int nt = (idx >> 9) & 7;
  int kt = idx >> 12;
  int k = kt * 32 + (L >> 4) * 8 + j;
  int n = nt * 16 + (L & 15);
  float v = (k < KROWS) ? W[(size_t)k * 128 + n] : 0.f;
  packed[idx] = (bf16_t)v;
}

// ---------------------------------------------------------------------------
// Edge MLP via bf16 MFMA + segment max — barrier-free, wave-autonomous.
// RACE FIX vs round 4: explicit s_waitcnt lgkmcnt(0) between the wave's LDS
// zero (ds_write_b128) and its LDS atomics (ds_max_u32), and between atomics
// and LDS reads. Round 3's __syncthreads() provided this drain implicitly;
// same-wave DS-pipe ordering across op types is NOT guaranteed when the
// atomic hits bytes written by another lane's portion of the b128 store.
// ---------------------------------------------------------------------------
__global__ __launch_bounds__(256, 4) void edge_mlp_mfma(
    const bf16_t* __restrict__ featsb,   // N x 128 bf16
    const float* __restrict__ add_info,  // E x 4
    const int* __restrict__ nbr, const int* __restrict__ segs,
    const bf16_t* __restrict__ Wpk,      // packed 5*8*64*8 bf16
    const float* __restrict__ bb,
    float* __restrict__ pooled, int E)
{
  __shared__ unsigned red[4 * RW * 128];   // 16 KB, per-wave private regions
  __shared__ int segof_s[4][RW];

  const int tid  = threadIdx.x;
  const int e0   = blockIdx.x * TEB;
  const int lane = tid & 63;
  const int w    = tid >> 6;      // wave 0..3
  const int q    = lane >> 4;     // quad 0..3
  const int ln   = lane & 15;

  const int ebase = w * 32;
  const int erow0 = ebase + ln;        // m-tile 0 row
  const int erow1 = ebase + 16 + ln;   // m-tile 1 row
  const int eg0 = e0 + erow0;
  const int eg1 = e0 + erow1;

  // ---- 1. neighbor indices, then issue all gathers ASAP ----
  const int nb0 = (eg0 < E) ? nbr[eg0] : 0;
  const int nb1 = (eg1 < E) ? nbr[eg1] : 0;
  const bf16_t* aptr0 = featsb + (size_t)nb0 * 128 + q * 8;
  const bf16_t* aptr1 = featsb + (size_t)nb1 * 128 + q * 8;
  bf16x8 a0[4], a1[4];
  #pragma unroll
  for (int kt = 0; kt < 4; ++kt) {
    a0[kt] = *reinterpret_cast<const bf16x8*>(aptr0 + kt * 32);
    a1[kt] = *reinterpret_cast<const bf16x8*>(aptr1 + kt * 32);
  }
  bf16x8 ax0, ax1;
  #pragma unroll
  for (int j = 0; j < 8; ++j) { ax0[j] = (bf16_t)0.f; ax1[j] = (bf16_t)0.f; }
  if (q == 0) {
    if (eg0 < E) {
      float4 ai = *reinterpret_cast<const float4*>(add_info + (size_t)eg0 * 4);
      ax0[0] = (bf16_t)ai.x; ax0[1] = (bf16_t)ai.y; ax0[2] = (bf16_t)ai.z; ax0[3] = (bf16_t)ai.w;
    }
    if (eg1 < E) {
      float4 ai = *reinterpret_cast<const float4*>(add_info + (size_t)eg1 * 4);
      ax1[0] = (bf16_t)ai.x; ax1[1] = (bf16_t)ai.y; ax1[2] = (bf16_t)ai.z; ax1[3] = (bf16_t)ai.w;
    }
  }

  // ---- 2. zero own reduce region ----
  {
    uint4* rv = reinterpret_cast<uint4*>(&red[w * RW * 128 + lane * 16]);
    uint4 z = make_uint4(0u, 0u, 0u, 0u);
    rv[0] = z; rv[1] = z; rv[2] = z; rv[3] = z;
  }
  // drain the zero writes before any same-wave LDS atomic can touch them
  asm volatile("s_waitcnt lgkmcnt(0)" ::: "memory");

  // ---- 3. per-wave segment ranks (lanes 0..31 own edges) ----
  int myseg = INT_MIN;
  int flag = 0;
  if (lane < 32) {
    int e = e0 + ebase + lane;
    myseg = (e < E) ? segs[e] : INT_MIN;
    if (lane == 0) {
      flag = 1;
    } else {
      int ep = e - 1;
      int prevseg = (ep < E) ? segs[ep] : INT_MIN;
      flag = (myseg != prevseg) ? 1 : 0;
    }
  }
  unsigned long long b = __ballot(flag);
  const int ndw = __popcll(b);                               // uniform in wave
  int rank = 0;
  if (lane < 32)
    rank = __popcll(b & ((2ull << lane) - 1)) - 1;           // 0-based
  if (lane < 32 && flag && rank < RW) segof_s[w][rank] = myseg;

  // ranks for the 8 rows this thread owns
  int rks[2][4];
  #pragma unroll
  for (int mt = 0; mt < 2; ++mt)
    #pragma unroll
    for (int r = 0; r < 4; ++r)
      rks[mt][r] = __shfl(rank, mt * 16 + q * 4 + r);

  // ---- 4. bias ----
  float bbv[8];
  #pragma unroll
  for (int nt = 0; nt < 8; ++nt) bbv[nt] = bb[nt * 16 + ln];

  // ---- 5. MFMA chain (waits on gathers) ----
  f32x4 acc[2][8];
  #pragma unroll
  for (int mt = 0; mt < 2; ++mt)
    #pragma unroll
    for (int nt = 0; nt < 8; ++nt)
      #pragma unroll
      for (int r = 0; r < 4; ++r) acc[mt][nt][r] = 0.f;

  const bf16x8* Wp = reinterpret_cast<const bf16x8*>(Wpk);
  #pragma unroll
  for (int kt = 0; kt < 4; ++kt) {
    #pragma unroll
    for (int nt = 0; nt < 8; ++nt) {
      bf16x8 bfrag = Wp[(kt * 8 + nt) * 64 + lane];
      acc[0][nt] = __builtin_amdgcn_mfma_f32_16x16x32_bf16(a0[kt], bfrag, acc[0][nt], 0, 0, 0);
      acc[1][nt] = __builtin_amdgcn_mfma_f32_16x16x32_bf16(a1[kt], bfrag, acc[1][nt], 0, 0, 0);
    }
  }
  #pragma unroll
  for (int nt = 0; nt < 8; ++nt) {
    bf16x8 bfrag = Wp[(4 * 8 + nt) * 64 + lane];
    acc[0][nt] = __builtin_amdgcn_mfma_f32_16x16x32_bf16(ax0, bfrag, acc[0][nt], 0, 0, 0);
    acc[1][nt] = __builtin_amdgcn_mfma_f32_16x16x32_bf16(ax1, bfrag, acc[1][nt], 0, 0, 0);
  }

  unsigned* pooled_u = reinterpret_cast<unsigned*>(pooled);

  if (ndw <= RW) {
    // ---- 6a. run-length reduce into own LDS region ----
    #pragma unroll
    for (int mt = 0; mt < 2; ++mt) {
      #pragma unroll
      for (int nt = 0; nt < 8; ++nt) {
        int col = nt * 16 + ln;
        float vmax = 0.f;
        int prev = -1;
        #pragma unroll
        for (int r = 0; r < 4; ++r) {
          float v = fmaxf(acc[mt][nt][r] + bbv[nt], 0.f);
          int rk = rks[mt][r];
          if (rk == prev) {
            vmax = fmaxf(vmax, v);
          } else {
            if (prev >= 0 && vmax > 0.f)
              atomicMax(&red[(w * RW + prev) * 128 + col], __float_as_uint(vmax));
            prev = rk; vmax = v;
          }
        }
        if (vmax > 0.f)
          atomicMax(&red[(w * RW + prev) * 128 + col], __float_as_uint(vmax));
      }
    }
    // drain atomics before reading the region back
    asm volatile("s_waitcnt lgkmcnt(0)" ::: "memory");
    // ---- 7a. scatter: one global atomic per (run, col), skip zeros ----
    for (int d = 0; d < ndw; ++d) {
      int s = segof_s[w][d];
      if (s != INT_MIN) {
        unsigned v0 = red[(w * RW + d) * 128 + lane];
        unsigned v1 = red[(w * RW + d) * 128 + 64 + lane];
        if (v0) atomicMax(&pooled_u[(size_t)s * 128 + lane], v0);
        if (v1) atomicMax(&pooled_u[(size_t)s * 128 + 64 + lane], v1);
      }
    }
  } else {
    // ---- 6b. rare: many tiny segments -> direct global atomics ----
    int sgs[2][4];
    #pragma unroll
    for (int mt = 0; mt < 2; ++mt)
      #pragma unroll
      for (int r = 0; r < 4; ++r)
        sgs[mt][r] = __shfl(myseg, mt * 16 + q * 4 + r);
    #pragma unroll
    for (int mt = 0; mt < 2; ++mt) {
      #pragma unroll
      for (int nt = 0; nt < 8; ++nt) {
        int col = nt * 16 + ln;
        #pragma unroll
        for (int r = 0; r < 4; ++r) {
          float v = fmaxf(acc[mt][nt][r] + bbv[nt], 0.f);
          int s = sgs[mt][r];
          if (s != INT_MIN && v > 0.f)
            atomicMax(&pooled_u[(size_t)s * 128 + col], __float_as_uint(v));
        }
      }
    }
  }
}

// ---------------------------------------------------------------------------
// featsOut = featsIn + pooled @ Wo + bo via bf16 MFMA; emits bf16 copy.
// ---------------------------------------------------------------------------
__global__ __launch_bounds__(256, 4) void update_mfma(
    const float* __restrict__ featsIn, const float* __restrict__ pooled,
    const bf16_t* __restrict__ Wopk, const float* __restrict__ bo,
    float* __restrict__ featsOut, bf16_t* __restrict__ featsOutBf, int N)
{
  const int tid  = threadIdx.x;
  const int lane = tid & 63;
  const int w    = tid >> 6;
  const int q    = lane >> 4;
  const int ln   = lane & 15;
  const int n0   = blockIdx.x * 128 + w * 32;

  int r0 = n0 + ln, r1 = n0 + 16 + ln;
  int r0c = (r0 < N) ? r0 : (N - 1);
  int r1c = (r1 < N) ? r1 : (N - 1);
  const float* p0 = pooled + (size_t)r0c * 128 + q * 8;
  const float* p1 = pooled + (size_t)r1c * 128 + q * 8;

  f32x4 acc[2][8];
  #pragma unroll
  for (int mt = 0; mt < 2; ++mt)
    #pragma unroll
    for (int nt = 0; nt < 8; ++nt)
      #pragma unroll
      for (int r = 0; r < 4; ++r) acc[mt][nt][r] = 0.f;

  const bf16x8* Wp = reinterpret_cast<const bf16x8*>(Wopk);
  #pragma unroll
  for (int kt = 0; kt < 4; ++kt) {
    float4 f0a = *reinterpret_cast<const float4*>(p0 + kt * 32);
    float4 f0b = *reinterpret_cast<const float4*>(p0 + kt * 32 + 4);
    float4 f1a = *reinterpret_cast<const float4*>(p1 + kt * 32);
    float4 f1b = *reinterpret_cast<const float4*>(p1 + kt * 32 + 4);
    bf16x8 a0, a1;
    a0[0] = (bf16_t)f0a.x; a0[1] = (bf16_t)f0a.y; a0[2] = (bf16_t)f0a.z; a0[3] = (bf16_t)f0a.w;
    a0[4] = (bf16_t)f0b.x; a0[5] = (bf16_t)f0b.y; a0[6] = (bf16_t)f0b.z; a0[7] = (bf16_t)f0b.w;
    a1[0] = (bf16_t)f1a.x; a1[1] = (bf16_t)f1a.y; a1[2] = (bf16_t)f1a.z; a1[3] = (bf16_t)f1a.w;
    a1[4] = (bf16_t)f1b.x; a1[5] = (bf16_t)f1b.y; a1[6] = (bf16_t)f1b.z; a1[7] = (bf16_t)f1b.w;
    #pragma unroll
    for (int nt = 0; nt < 8; ++nt) {
      bf16x8 bfrag = Wp[(kt * 8 + nt) * 64 + lane];
      acc[0][nt] = __builtin_amdgcn_mfma_f32_16x16x32_bf16(a0, bfrag, acc[0][nt], 0, 0, 0);
      acc[1][nt] = __builtin_amdgcn_mfma_f32_16x16x32_bf16(a1, bfrag, acc[1][nt], 0, 0, 0);
    }
  }

  float bov[8];
  #pragma unroll
  for (int nt = 0; nt < 8; ++nt) bov[nt] = bo[nt * 16 + ln];

  #pragma unroll
  for (int mt = 0; mt < 2; ++mt) {
    #pragma unroll
    for (int r = 0; r < 4; ++r) {
      int row = n0 + mt * 16 + q * 4 + r;
      if (row < N) {
        #pragma unroll
        for (int nt = 0; nt < 8; ++nt) {
          int col = nt * 16 + ln;
          float o = featsIn[(size_t)row * 128 + col] + acc[mt][nt][r] + bov[nt];
          featsOut[(size_t)row * 128 + col] = o;
          featsOutBf[(size_t)row * 128 + col] = (bf16_t)o;
        }
      }
    }
  }
}

// ---------------------------------------------------------------------------
// Block-1 update FUSED with final projection:
// out[n] = (featsIn[n] + pooled[n] @ Wo + bo) . Wf + bf  — no feats write.
// ---------------------------------------------------------------------------
__global__ __launch_bounds__(256, 4) void update_final_mfma(
    const float* __restrict__ featsIn, const float* __restrict__ pooled,
    const bf16_t* __restrict__ Wopk, const float* __restrict__ bo,
    const float* __restrict__ Wf, const float* __restrict__ bf_,
    float* __restrict__ out, int N)
{
  const int tid  = threadIdx.x;
  const int lane = tid & 63;
  const int w    = tid >> 6;
  const int q    = lane >> 4;
  const int ln   = lane & 15;
  const int n0   = blockIdx.x * 128 + w * 32;

  int r0 = n0 + ln, r1 = n0 + 16 + ln;
  int r0c = (r0 < N) ? r0 : (N - 1);
  int r1c = (r1 < N) ? r1 : (N - 1);
  const float* p0 = pooled + (size_t)r0c * 128 + q * 8;
  const float* p1 = pooled + (size_t)r1c * 128 + q * 8;

  f32x4 acc[2][8];
  #pragma unroll
  for (int mt = 0; mt < 2; ++mt)
    #pragma unroll
    for (int nt = 0; nt < 8; ++nt)
      #pragma unroll
      for (int r = 0; r < 4; ++r) acc[mt][nt][r] = 0.f;

  const bf16x8* Wp = reinterpret_cast<const bf16x8*>(Wopk);
  #pragma unroll
  for (int kt = 0; kt < 4; ++kt) {
    float4 f0a = *reinterpret_cast<const float4*>(p0 + kt * 32);
    float4 f0b = *reinterpret_cast<const float4*>(p0 + kt * 32 + 4);
    float4 f1a = *reinterpret_cast<const float4*>(p1 + kt * 32);
    float4 f1b = *reinterpret_cast<const float4*>(p1 + kt * 32 + 4);
    bf16x8 a0, a1;
    a0[0] = (bf16_t)f0a.x; a0[1] = (bf16_t)f0a.y; a0[2] = (bf16_t)f0a.z; a0[3] = (bf16_t)f0a.w;
    a0[4] = (bf16_t)f0b.x; a0[5] = (bf16_t)f0b.y; a0[6] = (bf16_t)f0b.z; a0[7] = (bf16_t)f0b.w;
    a1[0] = (bf16_t)f1a.x; a1[1] = (bf16_t)f1a.y; a1[2] = (bf16_t)f1a.z; a1[3] = (bf16_t)f1a.w;
    a1[4] = (bf16_t)f1b.x; a1[5] = (bf16_t)f1b.y; a1[6] = (bf16_t)f1b.z; a1[7] = (bf16_t)f1b.w;
    #pragma unroll
    for (int nt = 0; nt < 8; ++nt) {
      bf16x8 bfrag = Wp[(kt * 8 + nt) * 64 + lane];
      acc[0][nt] = __builtin_amdgcn_mfma_f32_16x16x32_bf16(a0, bfrag, acc[0][nt], 0, 0, 0);
      acc[1][nt] = __builtin_amdgcn_mfma_f32_16x16x32_bf16(a1, bfrag, acc[1][nt], 0, 0, 0);
    }
  }

  float bov[8], wfv[8];
  #pragma unroll
  for (int nt = 0; nt < 8; ++nt) { bov[nt] = bo[nt * 16 + ln]; wfv[nt] = Wf[nt * 16 + ln]; }
  float bfs = bf_[0];

  #pragma unroll
  for (int mt = 0; mt < 2; ++mt) {
    #pragma unroll
    for (int r = 0; r < 4; ++r) {
      int row = n0 + mt * 16 + q * 4 + r;
      float partial = 0.f;
      if (row < N) {
        #pragma unroll
        for (int nt = 0; nt < 8; ++nt) {
          int col = nt * 16 + ln;
          float o = featsIn[(size_t)row * 128 + col] + acc[mt][nt][r] + bov[nt];
          partial += o * wfv[nt];
        }
      }
      partial += __shfl_xor(partial, 1);
      partial += __shfl_xor(partial, 2);
      partial += __shfl_xor(partial, 4);
      partial += __shfl_xor(partial, 8);
      if (ln == 0 && row < N) out[row] = partial + bfs;
    }
  }
}

// ---------------------------------------------------------------------------
extern "C" void kernel_launch(void* const* d_in, const int* in_sizes, int n_in,
                              void* d_out, int out_size, void* d_ws, size_t ws_size,
                              hipStream_t stream)
{
  const float* interpolated = (const float*)d_in[0];
  const float* add_info     = (const float*)d_in[1];
  const int*   nbr          = (const int*)d_in[2];
  const int*   segs         = (const int*)d_in[3];
  const float* Wb0 = (const float*)d_in[4];
  const float* bb0 = (const float*)d_in[5];
  const float* Wo0 = (const float*)d_in[6];
  const float* bo0 = (const float*)d_in[7];
  const float* Wb1 = (const float*)d_in[8];
  const float* bb1 = (const float*)d_in[9];
  const float* Wo1 = (const float*)d_in[10];
  const float* bo1 = (const float*)d_in[11];
  const float* Wf  = (const float*)d_in[12];
  const float* bf_ = (const float*)d_in[13];

  const int N = in_sizes[0] / 128;
  const int E = in_sizes[2];
  float* out = (float*)d_out;

  // workspace layout
  float* pooled = (float*)d_ws;                              // N*128 f32
  float* featsB = pooled + (size_t)N * 128;                  // N*128 f32
  bf16_t* featsA_bf = (bf16_t*)(featsB + (size_t)N * 128);   // N*128 bf16
  bf16_t* featsB_bf = featsA_bf + (size_t)N * 128;           // N*128 bf16
  bf16_t* Wpk0 = featsB_bf + (size_t)N * 128;                // 20480
  bf16_t* Wpk1 = Wpk0 + 5 * 8 * 64 * 8;                      // 20480
  bf16_t* Wopk0 = Wpk1 + 5 * 8 * 64 * 8;                     // 16384
  bf16_t* Wopk1 = Wopk0 + 4 * 8 * 64 * 8;                    // 16384

  const int egrid = (E + TEB - 1) / TEB;
  const int ugrid = (N + 127) / 128;
  const int zn4 = (N * 128) / 4;
  const int cgrid = ((N * 128) / 4 + 255) / 256;

  // prep
  pack_w_kernel<<<80, 256, 0, stream>>>(Wb0, Wpk0, 132, 5);
  pack_w_kernel<<<80, 256, 0, stream>>>(Wb1, Wpk1, 132, 5);
  pack_w_kernel<<<64, 256, 0, stream>>>(Wo0, Wopk0, 128, 4);
  pack_w_kernel<<<64, 256, 0, stream>>>(Wo1, Wopk1, 128, 4);
  convert_bf16_kernel<<<cgrid, 256, 0, stream>>>(interpolated, featsA_bf, N * 128);

  // block 0
  zero_kernel<<<1024, 256, 0, stream>>>((float4*)pooled, zn4);
  edge_mlp_mfma<<<egrid, 256, 0, stream>>>(featsA_bf, add_info, nbr, segs,
                                           Wpk0, bb0, pooled, E);
  update_mfma<<<ugrid, 256, 0, stream>>>(interpolated, pooled, Wopk0, bo0,
                                         featsB, featsB_bf, N);

  // block 1
  zero_kernel<<<1024, 256, 0, stream>>>((float4*)pooled, zn4);
  edge_mlp_mfma<<<egrid, 256, 0, stream>>>(featsB_bf, add_info, nbr, segs,
                                           Wpk1, bb1, pooled, E);
  update_final_mfma<<<ugrid, 256, 0, stream>>>(featsB, pooled, Wopk1, bo1,
                                               Wf, bf_, out, N);
}